// Round 1
// baseline (87.764 us; speedup 1.0000x reference)
//
#include <hip/hip_runtime.h>

typedef __bf16 bf16x8 __attribute__((ext_vector_type(8)));
typedef float f32x4 __attribute__((ext_vector_type(4)));
typedef unsigned short u16;

#define MFMA __builtin_amdgcn_mfma_f32_16x16x32_bf16

__device__ __forceinline__ u16 f2bf_bits(float f) {
  unsigned u = __builtin_bit_cast(unsigned, f);
  u = (u + 0x7fffu + ((u >> 16) & 1u)) >> 16;
  return (u16)u;
}
__device__ __forceinline__ __bf16 f2bf(float f) {
  u16 b = f2bf_bits(f);
  return __builtin_bit_cast(__bf16, b);
}

// LDS tiles: logical [R][64] bf16 rows (128 B). XOR-swizzle 16B chunks with row
// to kill the 128B-stride bank conflict on ds_read_b128 (guide G4).
__device__ __forceinline__ int swz_off(int row, int col) {
  return row * 64 + ((((col >> 3) ^ row) & 7) << 3) + (col & 7);
}
__device__ __forceinline__ bf16x8 lds_read8(const __bf16* buf, int row, int col) {
  return *(const bf16x8*)(buf + (row * 64 + ((((col >> 3) ^ row) & 7) << 3)));
}
__device__ __forceinline__ void lds_write8(__bf16* buf, int row, int col, bf16x8 v) {
  *(bf16x8*)(buf + (row * 64 + ((((col >> 3) ^ row) & 7) << 3))) = v;
}

// ---------------- prep: Wt[192][1024] bf16, row = output col (q0-63,k64-127,v128-191)
__global__ __launch_bounds__(256) void prep_w_kernel(
    const float* __restrict__ Wq, const float* __restrict__ Wk,
    const float* __restrict__ Wv, u16* __restrict__ wtg) {
  int idx = blockIdx.x * 256 + threadIdx.x;
  if (idx >= 192 * 1024) return;
  int row = idx >> 10, k = idx & 1023;
  const float* W = (row < 64) ? Wq : ((row < 128) ? Wk : Wv);
  int col = row & 63;
  wtg[idx] = f2bf_bits(W[(size_t)k * 64 + col]);
}

// RoPE a (lo,hi) column pair: lo holds col i (i<32), hi holds col i+32.
__device__ __forceinline__ void rope2(f32x4& lo, f32x4& hi, int i, float t_base) {
  // freq = 10000^(-i/32) = exp(-i * ln(10000)/32)
  float f = __expf(-(float)i * 0.28782313662425572f);
#pragma unroll
  for (int r = 0; r < 4; ++r) {
    float th = (t_base + (float)r) * f;
    float sn, cs;
    sincosf(th, &sn, &cs);
    float L = lo[r], H = hi[r];
    lo[r] = L * cs - H * sn;
    hi[r] = H * cs + L * sn;
  }
}

// ---------------- fused QKV projection + RoPE
// grid 256 (64 rows each), 512 threads = 8 waves (2 row-groups x 2 col-groups).
// Tile map keeps RoPE pairs (c, c+32) within one wave:
//   wc=0: tiles {0,1,2,3,4,6}  (q all, k cols 0-15 & 32-47)
//   wc=1: tiles {5,7,8,9,10,11} (k cols 16-31 & 48-63, v all)
__global__ __launch_bounds__(512) void qkv_rope_kernel(
    const float* __restrict__ x, const u16* __restrict__ wtg,
    u16* __restrict__ qg, u16* __restrict__ kg, u16* __restrict__ vtg) {
  __shared__ __bf16 xbuf[64 * 64];
  __shared__ __bf16 wbuf[192 * 64];
  const int tid = threadIdx.x;
  const int w = tid >> 6, l = tid & 63;
  const int wr = w >> 1, wc = w & 1;
  const int lr = l & 15, lg = l >> 4;
  const int r0 = blockIdx.x * 64;           // global row base
  const int b = r0 >> 11, t0 = r0 & 2047;   // batch, position base

  f32x4 acc[6];
#pragma unroll
  for (int j = 0; j < 6; ++j) acc[j] = (f32x4){0.f, 0.f, 0.f, 0.f};

  const int srow = tid >> 3, sc8 = tid & 7;
  for (int k0 = 0; k0 < 1024; k0 += 64) {
    {  // stage x 64x64 fp32 -> bf16 (1 chunk/thread)
      const float* src = x + (size_t)(r0 + srow) * 1024 + k0 + sc8 * 8;
      float4 f0 = *(const float4*)src;
      float4 f1 = *(const float4*)(src + 4);
      bf16x8 v;
      v[0] = f2bf(f0.x); v[1] = f2bf(f0.y); v[2] = f2bf(f0.z); v[3] = f2bf(f0.w);
      v[4] = f2bf(f1.x); v[5] = f2bf(f1.y); v[6] = f2bf(f1.z); v[7] = f2bf(f1.w);
      lds_write8(xbuf, srow, sc8 * 8, v);
    }
#pragma unroll
    for (int s = 0; s < 3; ++s) {  // stage Wt 192x64 (3 chunks/thread)
      int id = tid + s * 512;
      int rw = id >> 3, c8 = id & 7;
      bf16x8 v = *(const bf16x8*)(wtg + (size_t)rw * 1024 + k0 + c8 * 8);
      lds_write8(wbuf, rw, c8 * 8, v);
    }
    __syncthreads();
#pragma unroll
    for (int kk = 0; kk < 2; ++kk) {
      bf16x8 a = lds_read8(xbuf, wr * 16 + lr, kk * 32 + lg * 8);
#pragma unroll
      for (int j = 0; j < 6; ++j) {
        constexpr int TM[2][6] = {{0, 1, 2, 3, 4, 6}, {5, 7, 8, 9, 10, 11}};
        int tl = TM[wc][j];
        bf16x8 bb = lds_read8(wbuf, tl * 16 + lr, kk * 32 + lg * 8);
        acc[j] = MFMA(a, bb, acc[j], 0, 0, 0);
      }
    }
    __syncthreads();
  }

  const float t_base = (float)(t0 + wr * 16 + lg * 4);
  if (wc == 0) {
    rope2(acc[0], acc[2], lr, t_base);        // q cols lr / 32+lr
    rope2(acc[1], acc[3], 16 + lr, t_base);   // q cols 16+lr / 48+lr
    rope2(acc[4], acc[5], lr, t_base);        // k cols lr / 32+lr
#pragma unroll
    for (int j = 0; j < 4; ++j)
#pragma unroll
      for (int r = 0; r < 4; ++r) {
        float qv = acc[j][r] * 0.03125f;  // fold scale = 1024^-0.5 (exact 2^-5)
        qg[(size_t)(r0 + wr * 16 + lg * 4 + r) * 64 + j * 16 + lr] = f2bf_bits(qv);
      }
#pragma unroll
    for (int r = 0; r < 4; ++r) {
      size_t rowo = (size_t)(r0 + wr * 16 + lg * 4 + r) * 64;
      kg[rowo + lr] = f2bf_bits(acc[4][r]);
      kg[rowo + 32 + lr] = f2bf_bits(acc[5][r]);
    }
  } else {
    rope2(acc[0], acc[1], 16 + lr, t_base);   // k cols 16+lr / 48+lr
#pragma unroll
    for (int r = 0; r < 4; ++r) {
      size_t rowo = (size_t)(r0 + wr * 16 + lg * 4 + r) * 64;
      kg[rowo + 16 + lr] = f2bf_bits(acc[0][r]);
      kg[rowo + 48 + lr] = f2bf_bits(acc[1][r]);
    }
#pragma unroll
    for (int j = 2; j < 6; ++j) {             // v tiles -> transposed vt[b][d][t]
      int d = (j - 2) * 16 + lr;
      ushort4 uv;
      uv.x = f2bf_bits(acc[j][0]);
      uv.y = f2bf_bits(acc[j][1]);
      uv.z = f2bf_bits(acc[j][2]);
      uv.w = f2bf_bits(acc[j][3]);
      *(ushort4*)(vtg + (size_t)(b * 64 + d) * 2048 + t0 + wr * 16 + lg * 4) = uv;
    }
  }
}

// ---------------- flash attention (causal), 64 q-rows/block, 4 waves x 16 rows
__global__ __launch_bounds__(256) void attn_kernel(
    const u16* __restrict__ qg, const u16* __restrict__ kg,
    const u16* __restrict__ vtg, float* __restrict__ out) {
  __shared__ __bf16 kbuf[64 * 64];
  __shared__ __bf16 vbuf[64 * 64];
  __shared__ __bf16 pbuf[4 * 16 * 64];
  const int tid = threadIdx.x;
  const int w = tid >> 6, l = tid & 63;
  const int lr = l & 15, lg = l >> 4;
  const int b = blockIdx.x >> 5, qt = blockIdx.x & 31;
  const int q0 = qt * 64;
  const float NEG_INF = -__builtin_inff();

  const u16* qrow = qg + (size_t)(b * 2048 + q0 + w * 16 + lr) * 64;
  bf16x8 qf0 = *(const bf16x8*)(qrow + lg * 8);
  bf16x8 qf1 = *(const bf16x8*)(qrow + 32 + lg * 8);

  f32x4 acc_o[4];
#pragma unroll
  for (int n = 0; n < 4; ++n) acc_o[n] = (f32x4){0.f, 0.f, 0.f, 0.f};
  float m_r[4] = {NEG_INF, NEG_INF, NEG_INF, NEG_INF};
  float l_r[4] = {0.f, 0.f, 0.f, 0.f};

  for (int c = 0; c <= qt; ++c) {
#pragma unroll
    for (int s = 0; s < 2; ++s) {  // stage K tile + Vt tile (2 chunks each/thread)
      int id = tid + s * 256;
      int row = id >> 3, c8 = id & 7;
      bf16x8 kv = *(const bf16x8*)(kg + (size_t)(b * 2048 + c * 64 + row) * 64 + c8 * 8);
      lds_write8(kbuf, row, c8 * 8, kv);
      bf16x8 vv = *(const bf16x8*)(vtg + (size_t)(b * 64 + row) * 2048 + c * 64 + c8 * 8);
      lds_write8(vbuf, row, c8 * 8, vv);
    }
    __syncthreads();

    f32x4 s4[4];
#pragma unroll
    for (int nt = 0; nt < 4; ++nt) {  // S = Q K^T
      bf16x8 k0 = lds_read8(kbuf, nt * 16 + lr, lg * 8);
      bf16x8 k1 = lds_read8(kbuf, nt * 16 + lr, 32 + lg * 8);
      f32x4 t = (f32x4){0.f, 0.f, 0.f, 0.f};
      t = MFMA(qf0, k0, t, 0, 0, 0);
      t = MFMA(qf1, k1, t, 0, 0, 0);
      s4[nt] = t;
    }
    if (c == qt) {  // causal mask on diagonal tile
#pragma unroll
      for (int nt = 0; nt < 4; ++nt)
#pragma unroll
        for (int r = 0; r < 4; ++r) {
          int kv = nt * 16 + lr, qq = w * 16 + lg * 4 + r;
          if (kv > qq) s4[nt][r] = NEG_INF;
        }
    }
    // online softmax (rows live in 16-lane groups; reduce via shfl_xor 1,2,4,8)
    float osc[4];
#pragma unroll
    for (int r = 0; r < 4; ++r) {
      float pm = fmaxf(fmaxf(s4[0][r], s4[1][r]), fmaxf(s4[2][r], s4[3][r]));
      pm = fmaxf(pm, __shfl_xor(pm, 1));
      pm = fmaxf(pm, __shfl_xor(pm, 2));
      pm = fmaxf(pm, __shfl_xor(pm, 4));
      pm = fmaxf(pm, __shfl_xor(pm, 8));
      float mnew = fmaxf(m_r[r], pm);
      osc[r] = __expf(m_r[r] - mnew);
      m_r[r] = mnew;
    }
    float rs[4] = {0.f, 0.f, 0.f, 0.f};
#pragma unroll
    for (int nt = 0; nt < 4; ++nt)
#pragma unroll
      for (int r = 0; r < 4; ++r) {
        float p = __expf(s4[nt][r] - m_r[r]);
        s4[nt][r] = p;
        rs[r] += p;
      }
#pragma unroll
    for (int r = 0; r < 4; ++r) {
      float s = rs[r];
      s += __shfl_xor(s, 1);
      s += __shfl_xor(s, 2);
      s += __shfl_xor(s, 4);
      s += __shfl_xor(s, 8);
      l_r[r] = l_r[r] * osc[r] + s;
    }
    // P -> bf16 into per-wave LDS region (C-layout -> A-frag layout rearrange)
    __bf16* pw = pbuf + w * (16 * 64);
#pragma unroll
    for (int nt = 0; nt < 4; ++nt)
#pragma unroll
      for (int r = 0; r < 4; ++r)
        pw[swz_off(lg * 4 + r, nt * 16 + lr)] = f2bf(s4[nt][r]);
    __syncthreads();
#pragma unroll
    for (int nt = 0; nt < 4; ++nt)
#pragma unroll
      for (int r = 0; r < 4; ++r)
        acc_o[nt][r] *= osc[r];
#pragma unroll
    for (int h = 0; h < 2; ++h) {  // O += P V
      bf16x8 pf = lds_read8(pw, lr, h * 32 + lg * 8);
#pragma unroll
      for (int nt = 0; nt < 4; ++nt) {
        bf16x8 vf = lds_read8(vbuf, nt * 16 + lr, h * 32 + lg * 8);
        acc_o[nt] = MFMA(pf, vf, acc_o[nt], 0, 0, 0);
      }
    }
    __syncthreads();
  }
#pragma unroll
  for (int r = 0; r < 4; ++r) {
    float inv = 1.0f / l_r[r];
    size_t rowo = (size_t)(b * 2048 + q0 + w * 16 + lg * 4 + r) * 64;
#pragma unroll
    for (int nt = 0; nt < 4; ++nt)
      out[rowo + nt * 16 + lr] = acc_o[nt][r] * inv;
  }
}

extern "C" void kernel_launch(void* const* d_in, const int* in_sizes, int n_in,
                              void* d_out, int out_size, void* d_ws, size_t ws_size,
                              hipStream_t stream) {
  const float* x = (const float*)d_in[0];
  const float* Wq = (const float*)d_in[1];
  const float* Wk = (const float*)d_in[2];
  const float* Wv = (const float*)d_in[3];
  float* out = (float*)d_out;
  char* ws = (char*)d_ws;
  // ws layout: Wt bf16 [192][1024] | q bf16 [16384][64] | k bf16 [16384][64] | vt bf16 [8][64][2048]
  u16* wtg = (u16*)ws;                                  // 393216 B
  u16* qg = (u16*)(ws + 393216);                        // 2 MB
  u16* kg = (u16*)(ws + 393216 + 2097152);              // 2 MB
  u16* vtg = (u16*)(ws + 393216 + 2u * 2097152);        // 2 MB
  prep_w_kernel<<<dim3(768), dim3(256), 0, stream>>>(Wq, Wk, Wv, wtg);
  qkv_rope_kernel<<<dim3(256), dim3(512), 0, stream>>>(x, wtg, qg, kg, vtg);
  attn_kernel<<<dim3(256), dim3(256), 0, stream>>>(qg, kg, vtg, out);
}

// Round 2
// 69.593 us; speedup vs baseline: 1.2611x; 1.2611x over previous
//
#include <hip/hip_runtime.h>

typedef __bf16 bf16x8 __attribute__((ext_vector_type(8)));
typedef float f32x4 __attribute__((ext_vector_type(4)));
typedef unsigned short u16;

#define MFMA __builtin_amdgcn_mfma_f32_16x16x32_bf16

__device__ __forceinline__ u16 f2bf_bits(float f) {
  unsigned u = __builtin_bit_cast(unsigned, f);
  u = (u + 0x7fffu + ((u >> 16) & 1u)) >> 16;
  return (u16)u;
}
__device__ __forceinline__ __bf16 f2bf(float f) {
  u16 b = f2bf_bits(f);
  return __builtin_bit_cast(__bf16, b);
}

// LDS tiles: logical [R][64] bf16 rows (128 B). XOR-swizzle 16B chunks with row
// to kill the 128B-stride bank conflict on ds_read_b128 (guide G4).
__device__ __forceinline__ int swz_off(int row, int col) {
  return row * 64 + ((((col >> 3) ^ row) & 7) << 3) + (col & 7);
}
__device__ __forceinline__ bf16x8 lds_read8(const __bf16* buf, int row, int col) {
  return *(const bf16x8*)(buf + (row * 64 + ((((col >> 3) ^ row) & 7) << 3)));
}
__device__ __forceinline__ void lds_write8(__bf16* buf, int row, int col, bf16x8 v) {
  *(bf16x8*)(buf + (row * 64 + ((((col >> 3) ^ row) & 7) << 3))) = v;
}

// ---------------- prep: Wt[192][1024] bf16, row = output col (q0-63,k64-127,v128-191)
__global__ __launch_bounds__(256) void prep_w_kernel(
    const float* __restrict__ Wq, const float* __restrict__ Wk,
    const float* __restrict__ Wv, u16* __restrict__ wtg) {
  int idx = blockIdx.x * 256 + threadIdx.x;
  if (idx >= 192 * 1024) return;
  int row = idx >> 10, k = idx & 1023;
  const float* W = (row < 64) ? Wq : ((row < 128) ? Wk : Wv);
  int col = row & 63;
  wtg[idx] = f2bf_bits(W[(size_t)k * 64 + col]);
}

// RoPE a (lo,hi) column pair: lo holds col i (i<32), hi holds col i+32.
__device__ __forceinline__ void rope2(f32x4& lo, f32x4& hi, int i, float t_base) {
  float f = __expf(-(float)i * 0.28782313662425572f);  // 10000^(-i/32)
#pragma unroll
  for (int r = 0; r < 4; ++r) {
    float th = (t_base + (float)r) * f;
    float sn, cs;
    sincosf(th, &sn, &cs);
    float L = lo[r], H = hi[r];
    lo[r] = L * cs - H * sn;
    hi[r] = H * cs + L * sn;
  }
}

// ---------------- fused QKV projection + RoPE
__global__ __launch_bounds__(512) void qkv_rope_kernel(
    const float* __restrict__ x, const u16* __restrict__ wtg,
    u16* __restrict__ qg, u16* __restrict__ kg, u16* __restrict__ vtg) {
  __shared__ __bf16 xbuf[64 * 64];
  __shared__ __bf16 wbuf[192 * 64];
  const int tid = threadIdx.x;
  const int w = tid >> 6, l = tid & 63;
  const int wr = w >> 1, wc = w & 1;
  const int lr = l & 15, lg = l >> 4;
  const int r0 = blockIdx.x * 64;
  const int b = r0 >> 11, t0 = r0 & 2047;

  f32x4 acc[6];
#pragma unroll
  for (int j = 0; j < 6; ++j) acc[j] = (f32x4){0.f, 0.f, 0.f, 0.f};

  const int srow = tid >> 3, sc8 = tid & 7;
  for (int k0 = 0; k0 < 1024; k0 += 64) {
    {
      const float* src = x + (size_t)(r0 + srow) * 1024 + k0 + sc8 * 8;
      float4 f0 = *(const float4*)src;
      float4 f1 = *(const float4*)(src + 4);
      bf16x8 v;
      v[0] = f2bf(f0.x); v[1] = f2bf(f0.y); v[2] = f2bf(f0.z); v[3] = f2bf(f0.w);
      v[4] = f2bf(f1.x); v[5] = f2bf(f1.y); v[6] = f2bf(f1.z); v[7] = f2bf(f1.w);
      lds_write8(xbuf, srow, sc8 * 8, v);
    }
#pragma unroll
    for (int s = 0; s < 3; ++s) {
      int id = tid + s * 512;
      int rw = id >> 3, c8 = id & 7;
      bf16x8 v = *(const bf16x8*)(wtg + (size_t)rw * 1024 + k0 + c8 * 8);
      lds_write8(wbuf, rw, c8 * 8, v);
    }
    __syncthreads();
#pragma unroll
    for (int kk = 0; kk < 2; ++kk) {
      bf16x8 a = lds_read8(xbuf, wr * 16 + lr, kk * 32 + lg * 8);
#pragma unroll
      for (int j = 0; j < 6; ++j) {
        constexpr int TM[2][6] = {{0, 1, 2, 3, 4, 6}, {5, 7, 8, 9, 10, 11}};
        int tl = TM[wc][j];
        bf16x8 bb = lds_read8(wbuf, tl * 16 + lr, kk * 32 + lg * 8);
        acc[j] = MFMA(a, bb, acc[j], 0, 0, 0);
      }
    }
    __syncthreads();
  }

  const float t_base = (float)(t0 + wr * 16 + lg * 4);
  if (wc == 0) {
    rope2(acc[0], acc[2], lr, t_base);
    rope2(acc[1], acc[3], 16 + lr, t_base);
    rope2(acc[4], acc[5], lr, t_base);
#pragma unroll
    for (int j = 0; j < 4; ++j)
#pragma unroll
      for (int r = 0; r < 4; ++r) {
        float qv = acc[j][r] * 0.03125f;  // fold scale 1024^-0.5 = 2^-5
        qg[(size_t)(r0 + wr * 16 + lg * 4 + r) * 64 + j * 16 + lr] = f2bf_bits(qv);
      }
#pragma unroll
    for (int r = 0; r < 4; ++r) {
      size_t rowo = (size_t)(r0 + wr * 16 + lg * 4 + r) * 64;
      kg[rowo + lr] = f2bf_bits(acc[4][r]);
      kg[rowo + 32 + lr] = f2bf_bits(acc[5][r]);
    }
  } else {
    rope2(acc[0], acc[1], 16 + lr, t_base);
#pragma unroll
    for (int r = 0; r < 4; ++r) {
      size_t rowo = (size_t)(r0 + wr * 16 + lg * 4 + r) * 64;
      kg[rowo + 16 + lr] = f2bf_bits(acc[0][r]);
      kg[rowo + 48 + lr] = f2bf_bits(acc[1][r]);
    }
#pragma unroll
    for (int j = 2; j < 6; ++j) {
      int d = (j - 2) * 16 + lr;
      ushort4 uv;
      uv.x = f2bf_bits(acc[j][0]);
      uv.y = f2bf_bits(acc[j][1]);
      uv.z = f2bf_bits(acc[j][2]);
      uv.w = f2bf_bits(acc[j][3]);
      *(ushort4*)(vtg + (size_t)(b * 64 + d) * 2048 + t0 + wr * 16 + lg * 4) = uv;
    }
  }
}

// ---------------- flash attention, split-KV partials.
// grid = 8 * 32 * NCH; block (b, qt, ch) handles KV tiles [ch*CT, min(qt+1, ch*CT+CT)).
// Writes unnormalized O' (bf16, 64x64) + per-row m,l (f32) to ws.
__global__ __launch_bounds__(256) void attn_part_kernel(
    const u16* __restrict__ qg, const u16* __restrict__ kg,
    const u16* __restrict__ vtg, u16* __restrict__ opart,
    float* __restrict__ mlpart, int CT, int NCH) {
  const int idx = blockIdx.x;
  const int b = idx / (32 * NCH);
  const int rem = idx % (32 * NCH);
  const int qt = rem / NCH, ch = rem % NCH;
  const int t0v = ch * CT;
  if (t0v > qt) return;  // uniform early-exit (before any barrier)
  const int t1v = min(qt + 1, t0v + CT);

  __shared__ __bf16 kbuf[64 * 64];
  __shared__ __bf16 vbuf[64 * 64];
  __shared__ __bf16 pbuf[4 * 16 * 64];
  const int tid = threadIdx.x;
  const int w = tid >> 6, l = tid & 63;
  const int lr = l & 15, lg = l >> 4;
  const int q0 = qt * 64;
  const float NEG_INF = -__builtin_inff();

  const u16* qrow = qg + (size_t)(b * 2048 + q0 + w * 16 + lr) * 64;
  bf16x8 qf0 = *(const bf16x8*)(qrow + lg * 8);
  bf16x8 qf1 = *(const bf16x8*)(qrow + 32 + lg * 8);

  f32x4 acc_o[4];
#pragma unroll
  for (int n = 0; n < 4; ++n) acc_o[n] = (f32x4){0.f, 0.f, 0.f, 0.f};
  float m_r[4] = {NEG_INF, NEG_INF, NEG_INF, NEG_INF};
  float l_r[4] = {0.f, 0.f, 0.f, 0.f};

  for (int c = t0v; c < t1v; ++c) {
#pragma unroll
    for (int s = 0; s < 2; ++s) {
      int id = tid + s * 256;
      int row = id >> 3, c8 = id & 7;
      bf16x8 kv = *(const bf16x8*)(kg + (size_t)(b * 2048 + c * 64 + row) * 64 + c8 * 8);
      lds_write8(kbuf, row, c8 * 8, kv);
      bf16x8 vv = *(const bf16x8*)(vtg + (size_t)(b * 64 + row) * 2048 + c * 64 + c8 * 8);
      lds_write8(vbuf, row, c8 * 8, vv);
    }
    __syncthreads();

    f32x4 s4[4];
#pragma unroll
    for (int nt = 0; nt < 4; ++nt) {
      bf16x8 k0 = lds_read8(kbuf, nt * 16 + lr, lg * 8);
      bf16x8 k1 = lds_read8(kbuf, nt * 16 + lr, 32 + lg * 8);
      f32x4 t = (f32x4){0.f, 0.f, 0.f, 0.f};
      t = MFMA(qf0, k0, t, 0, 0, 0);
      t = MFMA(qf1, k1, t, 0, 0, 0);
      s4[nt] = t;
    }
    if (c == qt) {  // causal mask on diagonal tile
#pragma unroll
      for (int nt = 0; nt < 4; ++nt)
#pragma unroll
        for (int r = 0; r < 4; ++r) {
          int kv = nt * 16 + lr, qq = w * 16 + lg * 4 + r;
          if (kv > qq) s4[nt][r] = NEG_INF;
        }
    }
    float osc[4];
#pragma unroll
    for (int r = 0; r < 4; ++r) {
      float pm = fmaxf(fmaxf(s4[0][r], s4[1][r]), fmaxf(s4[2][r], s4[3][r]));
      pm = fmaxf(pm, __shfl_xor(pm, 1));
      pm = fmaxf(pm, __shfl_xor(pm, 2));
      pm = fmaxf(pm, __shfl_xor(pm, 4));
      pm = fmaxf(pm, __shfl_xor(pm, 8));
      float mnew = fmaxf(m_r[r], pm);
      osc[r] = __expf(m_r[r] - mnew);
      m_r[r] = mnew;
    }
    float rs[4] = {0.f, 0.f, 0.f, 0.f};
#pragma unroll
    for (int nt = 0; nt < 4; ++nt)
#pragma unroll
      for (int r = 0; r < 4; ++r) {
        float p = __expf(s4[nt][r] - m_r[r]);
        s4[nt][r] = p;
        rs[r] += p;
      }
#pragma unroll
    for (int r = 0; r < 4; ++r) {
      float s = rs[r];
      s += __shfl_xor(s, 1);
      s += __shfl_xor(s, 2);
      s += __shfl_xor(s, 4);
      s += __shfl_xor(s, 8);
      l_r[r] = l_r[r] * osc[r] + s;
    }
    __bf16* pw = pbuf + w * (16 * 64);
#pragma unroll
    for (int nt = 0; nt < 4; ++nt)
#pragma unroll
      for (int r = 0; r < 4; ++r)
        pw[swz_off(lg * 4 + r, nt * 16 + lr)] = f2bf(s4[nt][r]);
    __syncthreads();
#pragma unroll
    for (int nt = 0; nt < 4; ++nt)
#pragma unroll
      for (int r = 0; r < 4; ++r)
        acc_o[nt][r] *= osc[r];
#pragma unroll
    for (int h = 0; h < 2; ++h) {
      bf16x8 pf = lds_read8(pw, lr, h * 32 + lg * 8);
#pragma unroll
      for (int nt = 0; nt < 4; ++nt) {
        bf16x8 vf = lds_read8(vbuf, nt * 16 + lr, h * 32 + lg * 8);
        acc_o[nt] = MFMA(pf, vf, acc_o[nt], 0, 0, 0);
      }
    }
    __syncthreads();
  }

  const size_t slot = (size_t)(b * 32 + qt) * NCH + ch;
  u16* oslot = opart + slot * 4096;
#pragma unroll
  for (int r = 0; r < 4; ++r) {
    int row = w * 16 + lg * 4 + r;
#pragma unroll
    for (int nt = 0; nt < 4; ++nt)
      oslot[row * 64 + nt * 16 + lr] = f2bf_bits(acc_o[nt][r]);
  }
  if (lr == 0) {
#pragma unroll
    for (int r = 0; r < 4; ++r) {
      int row = w * 16 + lg * 4 + r;
      mlpart[slot * 128 + row] = m_r[r];
      mlpart[slot * 128 + 64 + row] = l_r[r];
    }
  }
}

// ---------------- combine partials: out = sum_c exp(m_c-M) O'_c / sum_c exp(m_c-M) l_c
__global__ __launch_bounds__(256) void attn_combine_kernel(
    const u16* __restrict__ opart, const float* __restrict__ mlpart,
    float* __restrict__ out, int CT, int NCH) {
  const int b = blockIdx.x >> 5, qt = blockIdx.x & 31;
  const int nv = qt / CT + 1;  // = ceil((qt+1)/CT)
  const int row = threadIdx.x >> 2;
  const int cseg = (threadIdx.x & 3) << 4;
  const size_t slot0 = (size_t)(b * 32 + qt) * NCH;

  float M = -__builtin_inff();
  for (int c = 0; c < nv; ++c) M = fmaxf(M, mlpart[(slot0 + c) * 128 + row]);

  float denom = 0.f;
  float accv[16];
#pragma unroll
  for (int j = 0; j < 16; ++j) accv[j] = 0.f;

  for (int c = 0; c < nv; ++c) {
    float mc = mlpart[(slot0 + c) * 128 + row];
    float lc = mlpart[(slot0 + c) * 128 + 64 + row];
    float wgt = __expf(mc - M);
    denom += wgt * lc;
    const bf16x8* p = (const bf16x8*)(opart + (slot0 + c) * 4096 + row * 64 + cseg);
    bf16x8 s0 = p[0], s1 = p[1];
#pragma unroll
    for (int j = 0; j < 8; ++j) {
      accv[j] += wgt * (float)s0[j];
      accv[8 + j] += wgt * (float)s1[j];
    }
  }
  float inv = 1.0f / denom;
  float* dst = out + ((size_t)(b * 2048 + qt * 64 + row)) * 64 + cseg;
#pragma unroll
  for (int v = 0; v < 4; ++v) {
    float4 o;
    o.x = accv[v * 4 + 0] * inv;
    o.y = accv[v * 4 + 1] * inv;
    o.z = accv[v * 4 + 2] * inv;
    o.w = accv[v * 4 + 3] * inv;
    *(float4*)(dst + v * 4) = o;
  }
}

extern "C" void kernel_launch(void* const* d_in, const int* in_sizes, int n_in,
                              void* d_out, int out_size, void* d_ws, size_t ws_size,
                              hipStream_t stream) {
  const float* x = (const float*)d_in[0];
  const float* Wq = (const float*)d_in[1];
  const float* Wk = (const float*)d_in[2];
  const float* Wv = (const float*)d_in[3];
  float* out = (float*)d_out;
  char* ws = (char*)d_ws;
  // ws layout: Wt bf16 [192][1024] | q bf16 | k bf16 | vt bf16 | Opart | mlpart
  u16* wtg = (u16*)ws;
  u16* qg = (u16*)(ws + 393216);
  u16* kg = (u16*)(ws + 393216 + 2097152);
  u16* vtg = (u16*)(ws + 393216 + 2u * 2097152);
  const size_t base = 393216 + 3u * 2097152;  // 6,684,672 B
  // pick largest split factor NCH (chunks per q-tile) that fits ws:
  // per slot: 64*64 bf16 O' (8192 B) + 128 f32 m/l (512 B); slots = 256*NCH
  int NCH = 8;
  while (NCH > 1 && base + (size_t)256 * NCH * 8704 > ws_size) NCH >>= 1;
  const int CT = 32 / NCH;
  u16* opart = (u16*)(ws + base);
  float* mlpart = (float*)(ws + base + (size_t)256 * NCH * 8192);

  prep_w_kernel<<<dim3(768), dim3(256), 0, stream>>>(Wq, Wk, Wv, wtg);
  qkv_rope_kernel<<<dim3(256), dim3(512), 0, stream>>>(x, wtg, qg, kg, vtg);
  attn_part_kernel<<<dim3(8 * 32 * NCH), dim3(256), 0, stream>>>(
      qg, kg, vtg, opart, mlpart, CT, NCH);
  attn_combine_kernel<<<dim3(256), dim3(256), 0, stream>>>(opart, mlpart, out, CT, NCH);
}

// Round 3
// 64.785 us; speedup vs baseline: 1.3547x; 1.0742x over previous
//
#include <hip/hip_runtime.h>

typedef __bf16 bf16x8 __attribute__((ext_vector_type(8)));
typedef float f32x4 __attribute__((ext_vector_type(4)));
typedef unsigned short u16;

#define MFMA __builtin_amdgcn_mfma_f32_16x16x32_bf16

__device__ __forceinline__ u16 f2bf_bits(float f) {
  unsigned u = __builtin_bit_cast(unsigned, f);
  u = (u + 0x7fffu + ((u >> 16) & 1u)) >> 16;
  return (u16)u;
}
__device__ __forceinline__ __bf16 f2bf(float f) {
  u16 b = f2bf_bits(f);
  return __builtin_bit_cast(__bf16, b);
}
__device__ __forceinline__ float bf2f(u16 b) {
  return __builtin_bit_cast(float, (unsigned)b << 16);
}

// LDS tiles: logical [R][64] bf16 rows (128 B). XOR-swizzle 16B chunks with row
// to kill the 128B-stride bank conflict on ds_read_b128 (guide G4).
__device__ __forceinline__ int swz_off(int row, int col) {
  return row * 64 + ((((col >> 3) ^ row) & 7) << 3) + (col & 7);
}
__device__ __forceinline__ bf16x8 lds_read8(const __bf16* buf, int row, int col) {
  return *(const bf16x8*)(buf + (row * 64 + ((((col >> 3) ^ row) & 7) << 3)));
}
__device__ __forceinline__ void lds_write8(__bf16* buf, int row, int col, bf16x8 v) {
  *(bf16x8*)(buf + (row * 64 + ((((col >> 3) ^ row) & 7) << 3))) = v;
}

// ---------------- prep: Wt[192][1024] bf16, row = output col (q0-63,k64-127,v128-191)
__global__ __launch_bounds__(256) void prep_w_kernel(
    const float* __restrict__ Wq, const float* __restrict__ Wk,
    const float* __restrict__ Wv, u16* __restrict__ wtg) {
  int idx = blockIdx.x * 256 + threadIdx.x;
  if (idx >= 192 * 1024) return;
  int row = idx >> 10, k = idx & 1023;
  const float* W = (row < 64) ? Wq : ((row < 128) ? Wk : Wv);
  int col = row & 63;
  wtg[idx] = f2bf_bits(W[(size_t)k * 64 + col]);
}

// RoPE a (lo,hi) column pair: lo holds col i (i<32), hi holds col i+32.
__device__ __forceinline__ void rope2(f32x4& lo, f32x4& hi, int i, float t_base) {
  float f = __expf(-(float)i * 0.28782313662425572f);  // 10000^(-i/32)
#pragma unroll
  for (int r = 0; r < 4; ++r) {
    float th = (t_base + (float)r) * f;
    float sn, cs;
    sincosf(th, &sn, &cs);
    float L = lo[r], H = hi[r];
    lo[r] = L * cs - H * sn;
    hi[r] = H * cs + L * sn;
  }
}

// ---------------- fused QKV projection + RoPE (double-buffered, 1 barrier/step)
__global__ __launch_bounds__(512) void qkv_rope_kernel(
    const float* __restrict__ x, const u16* __restrict__ wtg,
    u16* __restrict__ qg, u16* __restrict__ kg, u16* __restrict__ vtg) {
  __shared__ __bf16 xbuf[2][64 * 64];
  __shared__ __bf16 wbuf[2][192 * 64];
  const int tid = threadIdx.x;
  const int w = tid >> 6, l = tid & 63;
  const int wr = w >> 1, wc = w & 1;
  const int lr = l & 15, lg = l >> 4;
  const int r0 = blockIdx.x * 64;
  const int b = r0 >> 11, t0 = r0 & 2047;

  f32x4 acc[6];
#pragma unroll
  for (int j = 0; j < 6; ++j) acc[j] = (f32x4){0.f, 0.f, 0.f, 0.f};

  const int srow = tid >> 3, sc8 = tid & 7;

  float4 sx0, sx1;
  bf16x8 sw[3];
  auto stage_load = [&](int k0) {
    const float* src = x + (size_t)(r0 + srow) * 1024 + k0 + sc8 * 8;
    sx0 = *(const float4*)src;
    sx1 = *(const float4*)(src + 4);
#pragma unroll
    for (int s = 0; s < 3; ++s) {
      int id = tid + s * 512;
      sw[s] = *(const bf16x8*)(wtg + (size_t)(id >> 3) * 1024 + k0 + (id & 7) * 8);
    }
  };
  auto stage_write = [&](int bsel) {
    bf16x8 v;
    v[0] = f2bf(sx0.x); v[1] = f2bf(sx0.y); v[2] = f2bf(sx0.z); v[3] = f2bf(sx0.w);
    v[4] = f2bf(sx1.x); v[5] = f2bf(sx1.y); v[6] = f2bf(sx1.z); v[7] = f2bf(sx1.w);
    lds_write8(xbuf[bsel], srow, sc8 * 8, v);
#pragma unroll
    for (int s = 0; s < 3; ++s) {
      int id = tid + s * 512;
      lds_write8(wbuf[bsel], id >> 3, (id & 7) * 8, sw[s]);
    }
  };

  stage_load(0);
  stage_write(0);
  __syncthreads();
  for (int step = 0; step < 16; ++step) {
    const int cur = step & 1;
    if (step < 15) stage_load((step + 1) * 64);  // issue early; hides under MFMA
#pragma unroll
    for (int kk = 0; kk < 2; ++kk) {
      bf16x8 a = lds_read8(xbuf[cur], wr * 16 + lr, kk * 32 + lg * 8);
#pragma unroll
      for (int j = 0; j < 6; ++j) {
        constexpr int TM[2][6] = {{0, 1, 2, 3, 4, 6}, {5, 7, 8, 9, 10, 11}};
        int tl = TM[wc][j];
        bf16x8 bb = lds_read8(wbuf[cur], tl * 16 + lr, kk * 32 + lg * 8);
        acc[j] = MFMA(a, bb, acc[j], 0, 0, 0);
      }
    }
    if (step < 15) {
      stage_write(cur ^ 1);  // disjoint from bufs being read; skew bounded by barrier
      __syncthreads();
    }
  }

  const float t_base = (float)(t0 + wr * 16 + lg * 4);
  if (wc == 0) {
    rope2(acc[0], acc[2], lr, t_base);
    rope2(acc[1], acc[3], 16 + lr, t_base);
    rope2(acc[4], acc[5], lr, t_base);
#pragma unroll
    for (int j = 0; j < 4; ++j)
#pragma unroll
      for (int r = 0; r < 4; ++r) {
        float qv = acc[j][r] * 0.03125f;  // fold scale 1024^-0.5 = 2^-5
        qg[(size_t)(r0 + wr * 16 + lg * 4 + r) * 64 + j * 16 + lr] = f2bf_bits(qv);
      }
#pragma unroll
    for (int r = 0; r < 4; ++r) {
      size_t rowo = (size_t)(r0 + wr * 16 + lg * 4 + r) * 64;
      kg[rowo + lr] = f2bf_bits(acc[4][r]);
      kg[rowo + 32 + lr] = f2bf_bits(acc[5][r]);
    }
  } else {
    rope2(acc[0], acc[1], 16 + lr, t_base);
#pragma unroll
    for (int r = 0; r < 4; ++r) {
      size_t rowo = (size_t)(r0 + wr * 16 + lg * 4 + r) * 64;
      kg[rowo + 16 + lr] = f2bf_bits(acc[0][r]);
      kg[rowo + 48 + lr] = f2bf_bits(acc[1][r]);
    }
#pragma unroll
    for (int j = 2; j < 6; ++j) {
      int d = (j - 2) * 16 + lr;
      ushort4 uv;
      uv.x = f2bf_bits(acc[j][0]);
      uv.y = f2bf_bits(acc[j][1]);
      uv.z = f2bf_bits(acc[j][2]);
      uv.w = f2bf_bits(acc[j][3]);
      *(ushort4*)(vtg + (size_t)(b * 64 + d) * 2048 + t0 + wr * 16 + lg * 4) = uv;
    }
  }
}

// ---------------- flash attention split-KV partials (dbuf, issue-early, 1 barrier/iter)
__global__ __launch_bounds__(256) void attn_part_kernel(
    const u16* __restrict__ qg, const u16* __restrict__ kg,
    const u16* __restrict__ vtg, u16* __restrict__ opart,
    float* __restrict__ mlpart, int CT, int NCH) {
  const int idx = blockIdx.x;
  const int b = idx / (32 * NCH);
  const int rem = idx % (32 * NCH);
  const int qt = rem / NCH, ch = rem % NCH;
  const int t0v = ch * CT;
  if (t0v > qt) return;  // uniform early-exit (before any barrier)
  const int t1v = min(qt + 1, t0v + CT);

  __shared__ __bf16 kbuf[2][64 * 64];
  __shared__ __bf16 vbuf[2][64 * 64];
  __shared__ __bf16 pbuf[4 * 16 * 64];
  const int tid = threadIdx.x;
  const int w = tid >> 6, l = tid & 63;
  const int lr = l & 15, lg = l >> 4;
  const int q0 = qt * 64;
  const float NEG_INF = -__builtin_inff();

  const u16* qrow = qg + (size_t)(b * 2048 + q0 + w * 16 + lr) * 64;
  bf16x8 qf0 = *(const bf16x8*)(qrow + lg * 8);
  bf16x8 qf1 = *(const bf16x8*)(qrow + 32 + lg * 8);

  bf16x8 kr[2], vr[2];
  auto stage_load = [&](int c) {
#pragma unroll
    for (int s = 0; s < 2; ++s) {
      int id = tid + s * 256;
      int row = id >> 3, c8 = id & 7;
      kr[s] = *(const bf16x8*)(kg + (size_t)(b * 2048 + c * 64 + row) * 64 + c8 * 8);
      vr[s] = *(const bf16x8*)(vtg + (size_t)(b * 64 + row) * 2048 + c * 64 + c8 * 8);
    }
  };
  auto stage_write = [&](int bsel) {
#pragma unroll
    for (int s = 0; s < 2; ++s) {
      int id = tid + s * 256;
      int row = id >> 3, c8 = id & 7;
      lds_write8(kbuf[bsel], row, c8 * 8, kr[s]);
      lds_write8(vbuf[bsel], row, c8 * 8, vr[s]);
    }
  };

  f32x4 acc_o[4];
#pragma unroll
  for (int n = 0; n < 4; ++n) acc_o[n] = (f32x4){0.f, 0.f, 0.f, 0.f};
  float m_r[4] = {NEG_INF, NEG_INF, NEG_INF, NEG_INF};
  float l_r[4] = {0.f, 0.f, 0.f, 0.f};

  stage_load(t0v);
  stage_write(0);
  __syncthreads();

  for (int c = t0v; c < t1v; ++c) {
    const int cur = (c - t0v) & 1;
    const bool more = (c + 1 < t1v);
    if (more) stage_load(c + 1);  // issue early; hides under QK+softmax+PV

    f32x4 s4[4];
#pragma unroll
    for (int nt = 0; nt < 4; ++nt) {
      bf16x8 k0 = lds_read8(kbuf[cur], nt * 16 + lr, lg * 8);
      bf16x8 k1 = lds_read8(kbuf[cur], nt * 16 + lr, 32 + lg * 8);
      f32x4 t = (f32x4){0.f, 0.f, 0.f, 0.f};
      t = MFMA(qf0, k0, t, 0, 0, 0);
      t = MFMA(qf1, k1, t, 0, 0, 0);
      s4[nt] = t;
    }
    if (c == qt) {  // causal mask on diagonal tile
#pragma unroll
      for (int nt = 0; nt < 4; ++nt)
#pragma unroll
        for (int r = 0; r < 4; ++r) {
          int kv = nt * 16 + lr, qq = w * 16 + lg * 4 + r;
          if (kv > qq) s4[nt][r] = NEG_INF;
        }
    }
    float osc[4];
#pragma unroll
    for (int r = 0; r < 4; ++r) {
      float pm = fmaxf(fmaxf(s4[0][r], s4[1][r]), fmaxf(s4[2][r], s4[3][r]));
      pm = fmaxf(pm, __shfl_xor(pm, 1));
      pm = fmaxf(pm, __shfl_xor(pm, 2));
      pm = fmaxf(pm, __shfl_xor(pm, 4));
      pm = fmaxf(pm, __shfl_xor(pm, 8));
      float mnew = fmaxf(m_r[r], pm);
      osc[r] = __expf(m_r[r] - mnew);
      m_r[r] = mnew;
    }
    float rs[4] = {0.f, 0.f, 0.f, 0.f};
#pragma unroll
    for (int nt = 0; nt < 4; ++nt)
#pragma unroll
      for (int r = 0; r < 4; ++r) {
        float p = __expf(s4[nt][r] - m_r[r]);
        s4[nt][r] = p;
        rs[r] += p;
      }
#pragma unroll
    for (int r = 0; r < 4; ++r) {
      float s = rs[r];
      s += __shfl_xor(s, 1);
      s += __shfl_xor(s, 2);
      s += __shfl_xor(s, 4);
      s += __shfl_xor(s, 8);
      l_r[r] = l_r[r] * osc[r] + s;
    }
    // P -> bf16 via per-wave LDS region; wave-internal DS is in-order, no barrier.
    __bf16* pw = pbuf + w * (16 * 64);
#pragma unroll
    for (int nt = 0; nt < 4; ++nt)
#pragma unroll
      for (int r = 0; r < 4; ++r)
        pw[swz_off(lg * 4 + r, nt * 16 + lr)] = f2bf(s4[nt][r]);
#pragma unroll
    for (int nt = 0; nt < 4; ++nt)
#pragma unroll
      for (int r = 0; r < 4; ++r)
        acc_o[nt][r] *= osc[r];
#pragma unroll
    for (int h = 0; h < 2; ++h) {
      bf16x8 pf = lds_read8(pw, lr, h * 32 + lg * 8);
#pragma unroll
      for (int nt = 0; nt < 4; ++nt) {
        bf16x8 vf = lds_read8(vbuf[cur], nt * 16 + lr, h * 32 + lg * 8);
        acc_o[nt] = MFMA(pf, vf, acc_o[nt], 0, 0, 0);
      }
    }
    if (more) {
      stage_write(cur ^ 1);  // disjoint from bufs still being read by slow waves
      __syncthreads();
    }
  }

  const size_t slot = (size_t)(b * 32 + qt) * NCH + ch;
  u16* oslot = opart + slot * 4096;
#pragma unroll
  for (int r = 0; r < 4; ++r) {
    int row = w * 16 + lg * 4 + r;
#pragma unroll
    for (int nt = 0; nt < 4; ++nt)
      oslot[row * 64 + nt * 16 + lr] = f2bf_bits(acc_o[nt][r]);
  }
  if (lr == 0) {
#pragma unroll
    for (int r = 0; r < 4; ++r) {
      int row = w * 16 + lg * 4 + r;
      mlpart[slot * 128 + row] = m_r[r];
      mlpart[slot * 128 + 64 + row] = l_r[r];
    }
  }
}

// ---------------- combine partials: out = sum_c exp(m_c-M) O'_c / sum_c exp(m_c-M) l_c
// grid 8*32*4: each block handles 16 rows of one q-tile (4 cols/thread).
__global__ __launch_bounds__(256) void attn_combine_kernel(
    const u16* __restrict__ opart, const float* __restrict__ mlpart,
    float* __restrict__ out, int CT, int NCH) {
  const int bq = blockIdx.x >> 2;
  const int quarter = blockIdx.x & 3;
  const int b = bq >> 5, qt = bq & 31;
  const int nv = qt / CT + 1;
  const int row = quarter * 16 + (threadIdx.x >> 4);
  const int col = (threadIdx.x & 15) * 4;
  const size_t slot0 = (size_t)(b * 32 + qt) * NCH;

  float M = -__builtin_inff();
  for (int c = 0; c < nv; ++c) M = fmaxf(M, mlpart[(slot0 + c) * 128 + row]);

  float denom = 0.f;
  float acc[4] = {0.f, 0.f, 0.f, 0.f};
  for (int c = 0; c < nv; ++c) {
    float mc = mlpart[(slot0 + c) * 128 + row];
    float lc = mlpart[(slot0 + c) * 128 + 64 + row];
    float wgt = __expf(mc - M);
    denom += wgt * lc;
    ushort4 pv = *(const ushort4*)(opart + (slot0 + c) * 4096 + row * 64 + col);
    acc[0] += wgt * bf2f(pv.x);
    acc[1] += wgt * bf2f(pv.y);
    acc[2] += wgt * bf2f(pv.z);
    acc[3] += wgt * bf2f(pv.w);
  }
  float inv = 1.0f / denom;
  float4 o;
  o.x = acc[0] * inv; o.y = acc[1] * inv; o.z = acc[2] * inv; o.w = acc[3] * inv;
  *(float4*)(out + ((size_t)(b * 2048 + qt * 64 + row)) * 64 + col) = o;
}

extern "C" void kernel_launch(void* const* d_in, const int* in_sizes, int n_in,
                              void* d_out, int out_size, void* d_ws, size_t ws_size,
                              hipStream_t stream) {
  const float* x = (const float*)d_in[0];
  const float* Wq = (const float*)d_in[1];
  const float* Wk = (const float*)d_in[2];
  const float* Wv = (const float*)d_in[3];
  float* out = (float*)d_out;
  char* ws = (char*)d_ws;
  // ws layout: Wt bf16 [192][1024] | q bf16 | k bf16 | vt bf16 | Opart | mlpart
  u16* wtg = (u16*)ws;
  u16* qg = (u16*)(ws + 393216);
  u16* kg = (u16*)(ws + 393216 + 2097152);
  u16* vtg = (u16*)(ws + 393216 + 2u * 2097152);
  const size_t base = 393216 + 3u * 2097152;  // 6,684,672 B
  int NCH = 8;
  while (NCH > 1 && base + (size_t)256 * NCH * 8704 > ws_size) NCH >>= 1;
  const int CT = 32 / NCH;
  u16* opart = (u16*)(ws + base);
  float* mlpart = (float*)(ws + base + (size_t)256 * NCH * 8192);

  prep_w_kernel<<<dim3(768), dim3(256), 0, stream>>>(Wq, Wk, Wv, wtg);
  qkv_rope_kernel<<<dim3(256), dim3(512), 0, stream>>>(x, wtg, qg, kg, vtg);
  attn_part_kernel<<<dim3(8 * 32 * NCH), dim3(256), 0, stream>>>(
      qg, kg, vtg, opart, mlpart, CT, NCH);
  attn_combine_kernel<<<dim3(256 * 4), dim3(256), 0, stream>>>(opart, mlpart, out, CT, NCH);
}